// Round 9
// baseline (260.207 us; speedup 1.0000x reference)
//
#include <hip/hip_runtime.h>
#include <hip/hip_bf16.h>
#include <math.h>

typedef __bf16 bf16_t;
typedef bf16_t bf16x8 __attribute__((ext_vector_type(8)));
typedef bf16_t bf16x4 __attribute__((ext_vector_type(4)));
typedef float  f32x4  __attribute__((ext_vector_type(4)));

#define MFMA_16x16x32_BF16(a, b, c) __builtin_amdgcn_mfma_f32_16x16x32_bf16((a), (b), (c), 0, 0, 0)

static constexpr int BB = 4, TT = 2048, CC = 1024, HH = 16, HD = 64;
static constexpr int C3 = 3 * CC;   // 3072
static constexpr int MM = BB * TT;  // 8192 rows
static constexpr size_t SL = (size_t)BB * HH * TT * HD;  // elems per q/k/v slice

// async global->LDS, 16B per lane; LDS dest must be wave-uniform base (+lane*16 implicit)
__device__ __forceinline__ void gload16(const void* g, void* l) {
  __builtin_amdgcn_global_load_lds(
      (const __attribute__((address_space(1))) unsigned int*)g,
      (__attribute__((address_space(3))) unsigned int*)l, 16, 0, 0);
}

// ---------------- cast x (fp32) -> xb (bf16) ----------------
__global__ void cast_x_kernel(const float* __restrict__ x, bf16_t* __restrict__ xb, int n4) {
  int i = blockIdx.x * blockDim.x + threadIdx.x;
  if (i >= n4) return;
  float4 v = reinterpret_cast<const float4*>(x)[i];
  bf16x4 o;
  o[0] = (bf16_t)v.x; o[1] = (bf16_t)v.y; o[2] = (bf16_t)v.z; o[3] = (bf16_t)v.w;
  reinterpret_cast<bf16x4*>(xb)[i] = o;
}

// ------------- transpose+cast weights: in fp32 [R][Cn] -> out bf16 [Cn][R] -------------
__global__ void transpose_cast_kernel(const float* __restrict__ in, bf16_t* __restrict__ out,
                                      int R, int Cn) {
  __shared__ float tile[32][33];
  int c0 = blockIdx.x * 32, r0 = blockIdx.y * 32;
  int tx = threadIdx.x, ty = threadIdx.y;
#pragma unroll
  for (int i = 0; i < 4; ++i)
    tile[ty + 8 * i][tx] = in[(size_t)(r0 + ty + 8 * i) * Cn + c0 + tx];
  __syncthreads();
#pragma unroll
  for (int i = 0; i < 4; ++i)
    out[(size_t)(c0 + ty + 8 * i) * R + r0 + tx] = (bf16_t)tile[tx][ty + 8 * i];
}

// ------------- transpose vh [BH][T][64] -> vtt [BH][T/32][64][32] (tiled V^T) -------------
__global__ void transpose_v_kernel(const bf16_t* __restrict__ vh, bf16_t* __restrict__ vt) {
  __shared__ bf16_t tile[32][33];
  int t0 = blockIdx.x * 32, d0 = blockIdx.y * 32, bh = blockIdx.z;
  int tx = threadIdx.x, ty = threadIdx.y;
  const bf16_t* src = vh + (size_t)bh * TT * HD;
  bf16_t* dst = vt + (size_t)bh * TT * HD + (size_t)(t0 >> 5) * (HD * 32);
#pragma unroll
  for (int i = 0; i < 4; ++i)
    tile[ty + 8 * i][tx] = src[(size_t)(t0 + ty + 8 * i) * HD + d0 + tx];
  __syncthreads();
#pragma unroll
  for (int i = 0; i < 4; ++i)
    dst[(size_t)(d0 + ty + 8 * i) * 32 + tx] = tile[tx][ty + 8 * i];
}

// ------------- concat biases [bq | bkv] -> bias_cat[3072] -------------
__global__ void concat_bias_kernel(const float* __restrict__ bq, const float* __restrict__ bkv,
                                   float* __restrict__ dst) {
  int i = blockIdx.x * 256 + threadIdx.x;
  if (i >= 3072) return;
  const float* p = (i < 1024) ? (bq + i) : (bkv + i - 1024);
  dst[i] = *p;
}

// ---------------- GEMM: C[M,N] = A[M,K] * Bt[N,K]^T + bias ----------------
__device__ inline void store_out(float* p, float v)  { *p = v; }
__device__ inline void store_out(bf16_t* p, float v) { *p = (bf16_t)v; }

template <int SPLIT, typename OutT>
__global__ __launch_bounds__(256) void gemm_kernel(
    const bf16_t* __restrict__ A, const bf16_t* __restrict__ Bt, OutT* __restrict__ C,
    const float* __restrict__ bias, int M, int N, int K, int gx, int cpx) {
  __shared__ bf16_t As[128][32];
  __shared__ bf16_t Bs[128][32];
  const int tid = threadIdx.x;
  const int wid = tid >> 6, lane = tid & 63;
  const int lhi = lane >> 4, llo = lane & 15;
  const int wm = (wid >> 1) * 64, wn = (wid & 1) * 64;
  const int bid = blockIdx.x;
  const int swz = (bid & 7) * cpx + (bid >> 3);   // nwg % 8 == 0 for all our grids
  const int bx = swz % gx, by = swz / gx;
  const int m0 = bx * 128, n0 = by * 128;
  const int l4 = lane >> 2, c4 = lane & 3;

  const bf16_t* gA = A + (size_t)(m0 + wid * 32 + l4) * K + c4 * 8;
  const bf16_t* gB = Bt + (size_t)(n0 + wid * 32 + l4) * K + c4 * 8;
  bf16_t* lA = &As[wid * 32][0];   // wave-uniform
  bf16_t* lB = &Bs[wid * 32][0];

  f32x4 acc[4][4] = {};
  for (int k0 = 0; k0 < K; k0 += 32) {
    __syncthreads();
    gload16(gA + k0, lA);
    gload16(gA + k0 + (size_t)16 * K, lA + 16 * 32);
    gload16(gB + k0, lB);
    gload16(gB + k0 + (size_t)16 * K, lB + 16 * 32);
    __syncthreads();
    bf16x8 af[4], bfr[4];
#pragma unroll
    for (int mi = 0; mi < 4; ++mi) af[mi] = *(const bf16x8*)&As[wm + mi * 16 + llo][8 * lhi];
#pragma unroll
    for (int ni = 0; ni < 4; ++ni) bfr[ni] = *(const bf16x8*)&Bs[wn + ni * 16 + llo][8 * lhi];
#pragma unroll
    for (int mi = 0; mi < 4; ++mi)
#pragma unroll
      for (int ni = 0; ni < 4; ++ni)
        acc[mi][ni] = MFMA_16x16x32_BF16(af[mi], bfr[ni], acc[mi][ni]);
  }

#pragma unroll
  for (int mi = 0; mi < 4; ++mi) {
#pragma unroll
    for (int ni = 0; ni < 4; ++ni) {
      const int row0 = m0 + wm + mi * 16 + 4 * lhi;
      const int col  = n0 + wn + ni * 16 + llo;
      const float bv = bias[col];
      if constexpr (SPLIT) {
        const int sel = col >> 10, rem = col & 1023;
        const int hh = rem >> 6, dd = rem & 63;
#pragma unroll
        for (int r = 0; r < 4; ++r) {
          const int row = row0 + r;
          const int bb = row >> 11, t = row & 2047;
          size_t addr = ((((size_t)sel * BB + bb) * HH + hh) * TT + t) * HD + dd;
          ((bf16_t*)C)[addr] = (bf16_t)(acc[mi][ni][r] + bv);
        }
      } else {
#pragma unroll
        for (int r = 0; r < 4; ++r)
          store_out(&C[(size_t)(row0 + r) * N + col], acc[mi][ni][r] + bv);
      }
    }
  }
}

// ---------------- flash attention, ALiBi, causal ----------------
// 512 blocks x 512 thr (8 waves). Block = tile-pair {pr, 15-pr} of one (b,h):
// waves 0-3 -> tile jt=pr, waves 4-7 -> tile 15-pr (32 q-rows each). Pair-sum cost is
// uniform -> all blocks equal duration (r7 lesson), but the pair now runs in PARALLEL:
// 2 blocks/CU x 8 waves = 16 waves/CU resident (2x r7). Wave->SIMD round-robin puts
// one short + one long wave per SIMD per block.
// XCD mapping (r8 lesson, kept): bid&7 = x -> heads {x, 15-x}; K/V 4MB per XCD = L2-
// resident (FETCH 90->25 MB measured).
// Body (proven r7): KVBLK=64, inline K loads, V issued early (lands under softmax),
// static-max softmax p=exp2(s*C1 + mh2*(j-i) - M0), per-wave P tile, no barriers.
__global__ __launch_bounds__(512, 4) void attn_kernel(
    const bf16_t* __restrict__ qh,   // [BH][T][64]
    const bf16_t* __restrict__ kh,   // [BH][T][64]
    const bf16_t* __restrict__ vt,   // [BH][T/32][64][32] tiled V^T
    const float* __restrict__ alibi_m,
    bf16_t* __restrict__ y) {        // [B*T][CC]
  __shared__ bf16_t Plds[8][32][68];
  const int tid = threadIdx.x, wid = tid >> 6, lane = tid & 63;
  const int lhi = lane >> 4, llo = lane & 15;
  const int bid = blockIdx.x;
  const int x = bid & 7, i6 = bid >> 3;
  const int sel = i6 & 1, b = (i6 >> 1) & 3, pr = (i6 >> 3) & 7;
  const int h = sel ? (15 - x) : x;
  const int side = wid >> 2, iw = wid & 3;
  const int jt = side ? (15 - pr) : pr;
  const int bh = b * HH + h;
  const int q0 = jt * 128 + iw * 32;

  const float mh2 = alibi_m[h] * 1.44269504f;   // ALiBi slope in exp2 units
  const float C1 = 0.18033688f;                 // 0.125 * log2(e)
  const float M0 = 17.3f;                       // static max; p bounded, no overflow
  const int Dwin = (int)(40.0f / mh2);          // dropped keys: rel weight < ~2^-40

  const bf16_t* qbase = qh + (size_t)bh * TT * HD;
  const bf16_t* kbase = kh + (size_t)bh * TT * HD;
  const bf16_t* vbase = vt + (size_t)bh * TT * HD;

  bf16x8 qf[2][2];
#pragma unroll
  for (int f = 0; f < 2; ++f) {
    const bf16_t* qp = qbase + (size_t)(q0 + 16 * f + llo) * HD + 8 * lhi;
    qf[f][0] = *(const bf16x8*)qp;
    qf[f][1] = *(const bf16x8*)(qp + 32);
  }

  f32x4 acc[2][4] = {};
  float lsum[2][4] = {};
  int ks = q0 - Dwin; ks = (ks < 0) ? 0 : (ks & ~63);
  const int kv_end = ((q0 + 31) & ~63) + 64;
  const float bias0 = mh2 * (float)(llo - 4 * lhi - q0) - M0;

#pragma unroll 1
  for (int kv0 = ks; kv0 < kv_end; kv0 += 64) {
    // ---- QK^T over 64 kv (K loads inline, 4-chunk pipeline) ----
    f32x4 s[2][4];
#pragma unroll
    for (int c = 0; c < 4; ++c) {
      const bf16_t* kp = kbase + (size_t)(kv0 + 16 * c + llo) * HD + 8 * lhi;
      bf16x8 k0 = *(const bf16x8*)kp;
      bf16x8 k1 = *(const bf16x8*)(kp + 32);
      s[0][c] = MFMA_16x16x32_BF16(qf[0][0], k0, f32x4{});
      s[0][c] = MFMA_16x16x32_BF16(qf[0][1], k1, s[0][c]);
      s[1][c] = MFMA_16x16x32_BF16(qf[1][0], k0, f32x4{});
      s[1][c] = MFMA_16x16x32_BF16(qf[1][1], k1, s[1][c]);
    }
    // ---- V fragments (issue early; land under softmax) ----
    bf16x8 vv[4][2];
    {
      const bf16_t* vp = vbase + (size_t)(kv0 >> 5) * 2048 + (size_t)llo * 32 + 8 * lhi;
#pragma unroll
      for (int d = 0; d < 4; ++d) {
        vv[d][0] = *(const bf16x8*)(vp + d * 512);
        vv[d][1] = *(const bf16x8*)(vp + d * 512 + 2048);
      }
    }
    // ---- static-max softmax + causal mask ----
    const float tb0 = fmaf(mh2, (float)kv0, bias0);
    const int dbase = q0 + 4 * lhi - llo - kv0;   // keep iff 16c-16f-r <= dbase
#pragma unroll
    for (int f = 0; f < 2; ++f) {
#pragma unroll
      for (int c = 0; c < 4; ++c) {
#pragma unroll
        for (int r = 0; r < 4; ++r) {
          const int kc = 16 * c - 16 * f - r;
          float pv = exp2f(fmaf(s[f][c][r], C1, fmaf((float)kc, mh2, tb0)));
          pv = (kc <= dbase) ? pv : 0.f;
          lsum[f][r] += pv;
          Plds[wid][16 * f + 4 * lhi + r][16 * c + llo] = (bf16_t)pv;
        }
      }
    }
    // ---- PV ----
#pragma unroll
    for (int f = 0; f < 2; ++f) {
      const bf16x8 pa0 = *(const bf16x8*)&Plds[wid][16 * f + llo][8 * lhi];
      const bf16x8 pa1 = *(const bf16x8*)&Plds[wid][16 * f + llo][32 + 8 * lhi];
#pragma unroll
      for (int d = 0; d < 4; ++d) {
        acc[f][d] = MFMA_16x16x32_BF16(pa0, vv[d][0], acc[f][d]);
        acc[f][d] = MFMA_16x16x32_BF16(pa1, vv[d][1], acc[f][d]);
      }
    }
  }

  // ---- one l-reduction across the 16-lane row group; epilogue ----
#pragma unroll
  for (int f = 0; f < 2; ++f) {
    float rl[4];
#pragma unroll
    for (int r = 0; r < 4; ++r) {
#pragma unroll
      for (int off = 1; off < 16; off <<= 1)
        lsum[f][r] += __shfl_xor(lsum[f][r], off, 64);
      rl[r] = __builtin_amdgcn_rcpf(lsum[f][r]);
    }
#pragma unroll
    for (int d = 0; d < 4; ++d)
#pragma unroll
      for (int r = 0; r < 4; ++r) {
        const int row = q0 + 16 * f + 4 * lhi + r;
        y[(size_t)(b * TT + row) * CC + h * HD + 16 * d + llo] =
            (bf16_t)(acc[f][d][r] * rl[r]);
      }
  }
}

// ---------------- launch ----------------
extern "C" void kernel_launch(void* const* d_in, const int* in_sizes, int n_in,
                              void* d_out, int out_size, void* d_ws, size_t ws_size,
                              hipStream_t stream) {
  const float* x       = (const float*)d_in[0];
  const float* Wq      = (const float*)d_in[1];
  const float* bq      = (const float*)d_in[2];
  const float* Wkv     = (const float*)d_in[3];
  const float* bkv     = (const float*)d_in[4];
  const float* Wp      = (const float*)d_in[5];
  const float* bp      = (const float*)d_in[6];
  const float* alibi_m = (const float*)d_in[7];
  float* out = (float*)d_out;

  char* w = (char*)d_ws;
  bf16_t* xb   = (bf16_t*)w; w += (size_t)MM * CC * 2;        // 16.78 MB (reused as yb)
  bf16_t* qkvh = (bf16_t*)w; w += SL * 3 * 2;                 // 50.33 MB  [3][BH][T][64]
  bf16_t* btq  = (bf16_t*)w; w += (size_t)C3 * CC * 2;        //  6.29 MB
  bf16_t* wpt  = (bf16_t*)w; w += (size_t)CC * CC * 2;        //  2.10 MB
  bf16_t* vtb  = (bf16_t*)w; w += SL * 2;                     // 16.78 MB  [BH][T/32][64][32]
  float*  bcat = (float*)w;  w += (size_t)C3 * 4;             // 12 KB
  bf16_t* yb   = xb;  // xb dead after QKV GEMM -> alias

  dim3 tb(32, 8);
  cast_x_kernel<<<8192, 256, 0, stream>>>(x, xb, MM * CC / 4);
  transpose_cast_kernel<<<dim3(32, 32), tb, 0, stream>>>(Wq, btq, 1024, 1024);
  transpose_cast_kernel<<<dim3(64, 32), tb, 0, stream>>>(Wkv, btq + (size_t)1024 * 1024, 1024, 2048);
  transpose_cast_kernel<<<dim3(32, 32), tb, 0, stream>>>(Wp, wpt, 1024, 1024);
  concat_bias_kernel<<<12, 256, 0, stream>>>(bq, bkv, bcat);

  gemm_kernel<1, bf16_t><<<dim3(64 * 24), 256, 0, stream>>>(
      xb, btq, qkvh, bcat, MM, C3, CC, 64, (64 * 24) / 8);
  transpose_v_kernel<<<dim3(TT / 32, HD / 32, BB * HH), tb, 0, stream>>>(qkvh + 2 * SL, vtb);
  attn_kernel<<<dim3(512), 512, 0, stream>>>(qkvh, qkvh + SL, vtb, alibi_m, yb);
  gemm_kernel<0, float><<<dim3(64 * 8), 256, 0, stream>>>(
      yb, wpt, out, bp, MM, CC, CC, 64, (64 * 8) / 8);
}

// Round 10
// 220.897 us; speedup vs baseline: 1.1780x; 1.1780x over previous
//
#include <hip/hip_runtime.h>
#include <hip/hip_bf16.h>
#include <math.h>

typedef __bf16 bf16_t;
typedef bf16_t bf16x8 __attribute__((ext_vector_type(8)));
typedef bf16_t bf16x4 __attribute__((ext_vector_type(4)));
typedef float  f32x4  __attribute__((ext_vector_type(4)));

#define MFMA_16x16x32_BF16(a, b, c) __builtin_amdgcn_mfma_f32_16x16x32_bf16((a), (b), (c), 0, 0, 0)

static constexpr int BB = 4, TT = 2048, CC = 1024, HH = 16, HD = 64;
static constexpr int C3 = 3 * CC;   // 3072
static constexpr int MM = BB * TT;  // 8192 rows
static constexpr size_t SL = (size_t)BB * HH * TT * HD;  // elems per q/k/v slice

// async global->LDS, 16B per lane; LDS dest must be wave-uniform base (+lane*16 implicit)
__device__ __forceinline__ void gload16(const void* g, void* l) {
  __builtin_amdgcn_global_load_lds(
      (const __attribute__((address_space(1))) unsigned int*)g,
      (__attribute__((address_space(3))) unsigned int*)l, 16, 0, 0);
}

// ---------------- cast x (fp32) -> xb (bf16) ----------------
__global__ void cast_x_kernel(const float* __restrict__ x, bf16_t* __restrict__ xb, int n4) {
  int i = blockIdx.x * blockDim.x + threadIdx.x;
  if (i >= n4) return;
  float4 v = reinterpret_cast<const float4*>(x)[i];
  bf16x4 o;
  o[0] = (bf16_t)v.x; o[1] = (bf16_t)v.y; o[2] = (bf16_t)v.z; o[3] = (bf16_t)v.w;
  reinterpret_cast<bf16x4*>(xb)[i] = o;
}

// ------------- transpose+cast weights: in fp32 [R][Cn] -> out bf16 [Cn][R] -------------
__global__ void transpose_cast_kernel(const float* __restrict__ in, bf16_t* __restrict__ out,
                                      int R, int Cn) {
  __shared__ float tile[32][33];
  int c0 = blockIdx.x * 32, r0 = blockIdx.y * 32;
  int tx = threadIdx.x, ty = threadIdx.y;
#pragma unroll
  for (int i = 0; i < 4; ++i)
    tile[ty + 8 * i][tx] = in[(size_t)(r0 + ty + 8 * i) * Cn + c0 + tx];
  __syncthreads();
#pragma unroll
  for (int i = 0; i < 4; ++i)
    out[(size_t)(c0 + ty + 8 * i) * R + r0 + tx] = (bf16_t)tile[tx][ty + 8 * i];
}

// ------------- transpose vh [BH][T][64] -> vtt [BH][T/32][64][32] (tiled V^T) -------------
__global__ void transpose_v_kernel(const bf16_t* __restrict__ vh, bf16_t* __restrict__ vt) {
  __shared__ bf16_t tile[32][33];
  int t0 = blockIdx.x * 32, d0 = blockIdx.y * 32, bh = blockIdx.z;
  int tx = threadIdx.x, ty = threadIdx.y;
  const bf16_t* src = vh + (size_t)bh * TT * HD;
  bf16_t* dst = vt + (size_t)bh * TT * HD + (size_t)(t0 >> 5) * (HD * 32);
#pragma unroll
  for (int i = 0; i < 4; ++i)
    tile[ty + 8 * i][tx] = src[(size_t)(t0 + ty + 8 * i) * HD + d0 + tx];
  __syncthreads();
#pragma unroll
  for (int i = 0; i < 4; ++i)
    dst[(size_t)(d0 + ty + 8 * i) * 32 + tx] = tile[tx][ty + 8 * i];
}

// ------------- concat biases [bq | bkv] -> bias_cat[3072] -------------
__global__ void concat_bias_kernel(const float* __restrict__ bq, const float* __restrict__ bkv,
                                   float* __restrict__ dst) {
  int i = blockIdx.x * 256 + threadIdx.x;
  if (i >= 3072) return;
  const float* p = (i < 1024) ? (bq + i) : (bkv + i - 1024);
  dst[i] = *p;
}

// ---------------- GEMM: C[M,N] = A[M,K] * Bt[N,K]^T + bias ----------------
// BK=64 (half the barriers of BK=32), global_load_lds with SOURCE-swizzled slots
// (rule 21: dest linear, global col slot s8 = ((lane&7)^(lane>>3))*8) and XOR'd read
// slots (rs0 = (lhi^(llo&7))*16, kk-half = ^64) -> uniform 8 lanes/bank-group.
__device__ inline void store_out(float* p, float v)  { *p = v; }
__device__ inline void store_out(bf16_t* p, float v) { *p = (bf16_t)v; }

template <int SPLIT, typename OutT>
__global__ __launch_bounds__(256) void gemm_kernel(
    const bf16_t* __restrict__ A, const bf16_t* __restrict__ Bt, OutT* __restrict__ C,
    const float* __restrict__ bias, int M, int N, int K, int gx, int cpx) {
  __shared__ bf16_t As[128][64];
  __shared__ bf16_t Bs[128][64];
  const int tid = threadIdx.x;
  const int wid = tid >> 6, lane = tid & 63;
  const int lhi = lane >> 4, llo = lane & 15;
  const int wm = (wid >> 1) * 64, wn = (wid & 1) * 64;
  const int bid = blockIdx.x;
  const int swz = (bid & 7) * cpx + (bid >> 3);   // nwg % 8 == 0 for all our grids
  const int bx = swz % gx, by = swz / gx;
  const int m0 = bx * 128, n0 = by * 128;
  const int l8 = lane >> 3;                       // row within 8-row group
  const int s8 = ((lane & 7) ^ l8) * 8;           // swizzled source slot (elems)

  const bf16_t* gA = A + (size_t)(m0 + wid * 32 + l8) * K + s8;
  const bf16_t* gB = Bt + (size_t)(n0 + wid * 32 + l8) * K + s8;
  bf16_t* lA = &As[wid * 32][0];   // wave-uniform
  bf16_t* lB = &Bs[wid * 32][0];
  const int rs0 = (lhi ^ (llo & 7)) * 16;         // read slot (bytes); kk=1 -> ^64

  f32x4 acc[4][4] = {};
  for (int k0 = 0; k0 < K; k0 += 64) {
    __syncthreads();
#pragma unroll
    for (int g = 0; g < 4; ++g) {
      gload16(gA + k0 + (size_t)(8 * g) * K, lA + 8 * g * 64);
      gload16(gB + k0 + (size_t)(8 * g) * K, lB + 8 * g * 64);
    }
    __syncthreads();
#pragma unroll
    for (int kk = 0; kk < 2; ++kk) {
      const int ro = rs0 ^ (kk * 64);
      bf16x8 af[4], bfr[4];
#pragma unroll
      for (int mi = 0; mi < 4; ++mi)
        af[mi] = *(const bf16x8*)((const char*)&As[wm + mi * 16 + llo][0] + ro);
#pragma unroll
      for (int ni = 0; ni < 4; ++ni)
        bfr[ni] = *(const bf16x8*)((const char*)&Bs[wn + ni * 16 + llo][0] + ro);
#pragma unroll
      for (int mi = 0; mi < 4; ++mi)
#pragma unroll
        for (int ni = 0; ni < 4; ++ni)
          acc[mi][ni] = MFMA_16x16x32_BF16(af[mi], bfr[ni], acc[mi][ni]);
    }
  }

#pragma unroll
  for (int mi = 0; mi < 4; ++mi) {
#pragma unroll
    for (int ni = 0; ni < 4; ++ni) {
      const int row0 = m0 + wm + mi * 16 + 4 * lhi;
      const int col  = n0 + wn + ni * 16 + llo;
      const float bv = bias[col];
      if constexpr (SPLIT) {
        const int sel = col >> 10, rem = col & 1023;
        const int hh = rem >> 6, dd = rem & 63;
#pragma unroll
        for (int r = 0; r < 4; ++r) {
          const int row = row0 + r;
          const int bb = row >> 11, t = row & 2047;
          size_t addr = ((((size_t)sel * BB + bb) * HH + hh) * TT + t) * HD + dd;
          ((bf16_t*)C)[addr] = (bf16_t)(acc[mi][ni][r] + bv);
        }
      } else {
#pragma unroll
        for (int r = 0; r < 4; ++r)
          store_out(&C[(size_t)(row0 + r) * N + col], acc[mi][ni][r] + bv);
      }
    }
  }
}

// ---------------- flash attention, ALiBi, causal ----------------
// 512 blocks x 512 thr (8 waves). Block = tile-pair {pr, 15-pr} of one (b,h):
// waves 0-3 -> tile jt=pr, waves 4-7 -> 15-pr. Uniform block cost; 2 blocks/CU x
// 8 waves = 16 waves/CU resident. launch_bounds(512,2): cap tier 128 VGPR (body
// needs ~108, r7-measured) -> NO spill (r9's (512,4) forced 64 VGPR + 13MB spill).
// XCD mapping (r8, kept): bid&7 = x -> heads {x, 15-x}; K/V 4MB per XCD L2.
// Body (proven r7): KVBLK=64, inline K loads, V issued early, static-max softmax,
// per-wave P tile, no barriers.
__global__ __launch_bounds__(512, 2) void attn_kernel(
    const bf16_t* __restrict__ qh,   // [BH][T][64]
    const bf16_t* __restrict__ kh,   // [BH][T][64]
    const bf16_t* __restrict__ vt,   // [BH][T/32][64][32] tiled V^T
    const float* __restrict__ alibi_m,
    bf16_t* __restrict__ y) {        // [B*T][CC]
  __shared__ bf16_t Plds[8][32][68];
  const int tid = threadIdx.x, wid = tid >> 6, lane = tid & 63;
  const int lhi = lane >> 4, llo = lane & 15;
  const int bid = blockIdx.x;
  const int x = bid & 7, i6 = bid >> 3;
  const int sel = i6 & 1, b = (i6 >> 1) & 3, pr = (i6 >> 3) & 7;
  const int h = sel ? (15 - x) : x;
  const int side = wid >> 2, iw = wid & 3;
  const int jt = side ? (15 - pr) : pr;
  const int bh = b * HH + h;
  const int q0 = jt * 128 + iw * 32;

  const float mh2 = alibi_m[h] * 1.44269504f;   // ALiBi slope in exp2 units
  const float C1 = 0.18033688f;                 // 0.125 * log2(e)
  const float M0 = 17.3f;                       // static max; p bounded, no overflow
  const int Dwin = (int)(40.0f / mh2);          // dropped keys: rel weight < ~2^-40

  const bf16_t* qbase = qh + (size_t)bh * TT * HD;
  const bf16_t* kbase = kh + (size_t)bh * TT * HD;
  const bf16_t* vbase = vt + (size_t)bh * TT * HD;

  bf16x8 qf[2][2];
#pragma unroll
  for (int f = 0; f < 2; ++f) {
    const bf16_t* qp = qbase + (size_t)(q0 + 16 * f + llo) * HD + 8 * lhi;
    qf[f][0] = *(const bf16x8*)qp;
    qf[f][1] = *(const bf16x8*)(qp + 32);
  }

  f32x4 acc[2][4] = {};
  float lsum[2][4] = {};
  int ks = q0 - Dwin; ks = (ks < 0) ? 0 : (ks & ~63);
  const int kv_end = ((q0 + 31) & ~63) + 64;
  const float bias0 = mh2 * (float)(llo - 4 * lhi - q0) - M0;

#pragma unroll 1
  for (int kv0 = ks; kv0 < kv_end; kv0 += 64) {
    // ---- QK^T over 64 kv (K loads inline, 4-chunk pipeline) ----
    f32x4 s[2][4];
#pragma unroll
    for (int c = 0; c < 4; ++c) {
      const bf16_t* kp = kbase + (size_t)(kv0 + 16 * c + llo) * HD + 8 * lhi;
      bf16x8 k0 = *(const bf16x8*)kp;
      bf16x8 k1 = *(const bf16x8*)(kp + 32);
      s[0][c] = MFMA_16x16x32_BF16(qf[0][0], k0, f32x4{});
      s[0][c] = MFMA_16x16x32_BF16(qf[0][1], k1, s[0][c]);
      s[1][c] = MFMA_16x16x32_BF16(qf[1][0], k0, f32x4{});
      s[1][c] = MFMA_16x16x32_BF16(qf[1][1], k1, s[1][c]);
    }
    // ---- V fragments (issue early; land under softmax) ----
    bf16x8 vv[4][2];
    {
      const bf16_t* vp = vbase + (size_t)(kv0 >> 5) * 2048 + (size_t)llo * 32 + 8 * lhi;
#pragma unroll
      for (int d = 0; d < 4; ++d) {
        vv[d][0] = *(const bf16x8*)(vp + d * 512);
        vv[d][1] = *(const bf16x8*)(vp + d * 512 + 2048);
      }
    }
    // ---- static-max softmax + causal mask ----
    const float tb0 = fmaf(mh2, (float)kv0, bias0);
    const int dbase = q0 + 4 * lhi - llo - kv0;   // keep iff 16c-16f-r <= dbase
#pragma unroll
    for (int f = 0; f < 2; ++f) {
#pragma unroll
      for (int c = 0; c < 4; ++c) {
#pragma unroll
        for (int r = 0; r < 4; ++r) {
          const int kc = 16 * c - 16 * f - r;
          float pv = exp2f(fmaf(s[f][c][r], C1, fmaf((float)kc, mh2, tb0)));
          pv = (kc <= dbase) ? pv : 0.f;
          lsum[f][r] += pv;
          Plds[wid][16 * f + 4 * lhi + r][16 * c + llo] = (bf16_t)pv;
        }
      }
    }
    // ---- PV ----
#pragma unroll
    for (int f = 0; f < 2; ++f) {
      const bf16x8 pa0 = *(const bf16x8*)&Plds[wid][16 * f + llo][8 * lhi];
      const bf16x8 pa1 = *(const bf16x8*)&Plds[wid][16 * f + llo][32 + 8 * lhi];
#pragma unroll
      for (int d = 0; d < 4; ++d) {
        acc[f][d] = MFMA_16x16x32_BF16(pa0, vv[d][0], acc[f][d]);
        acc[f][d] = MFMA_16x16x32_BF16(pa1, vv[d][1], acc[f][d]);
      }
    }
  }

  // ---- one l-reduction across the 16-lane row group; epilogue ----
#pragma unroll
  for (int f = 0; f < 2; ++f) {
    float rl[4];
#pragma unroll
    for (int r = 0; r < 4; ++r) {
#pragma unroll
      for (int off = 1; off < 16; off <<= 1)
        lsum[f][r] += __shfl_xor(lsum[f][r], off, 64);
      rl[r] = __builtin_amdgcn_rcpf(lsum[f][r]);
    }
#pragma unroll
    for (int d = 0; d < 4; ++d)
#pragma unroll
      for (int r = 0; r < 4; ++r) {
        const int row = q0 + 16 * f + 4 * lhi + r;
        y[(size_t)(b * TT + row) * CC + h * HD + 16 * d + llo] =
            (bf16_t)(acc[f][d][r] * rl[r]);
      }
  }
}

// ---------------- launch ----------------
extern "C" void kernel_launch(void* const* d_in, const int* in_sizes, int n_in,
                              void* d_out, int out_size, void* d_ws, size_t ws_size,
                              hipStream_t stream) {
  const float* x       = (const float*)d_in[0];
  const float* Wq      = (const float*)d_in[1];
  const float* bq      = (const float*)d_in[2];
  const float* Wkv     = (const float*)d_in[3];
  const float* bkv     = (const float*)d_in[4];
  const float* Wp      = (const float*)d_in[5];
  const float* bp      = (const float*)d_in[6];
  const float* alibi_m = (const float*)d_in[7];
  float* out = (float*)d_out;

  char* w = (char*)d_ws;
  bf16_t* xb   = (bf16_t*)w; w += (size_t)MM * CC * 2;        // 16.78 MB (reused as yb)
  bf16_t* qkvh = (bf16_t*)w; w += SL * 3 * 2;                 // 50.33 MB  [3][BH][T][64]
  bf16_t* btq  = (bf16_t*)w; w += (size_t)C3 * CC * 2;        //  6.29 MB
  bf16_t* wpt  = (bf16_t*)w; w += (size_t)CC * CC * 2;        //  2.10 MB
  bf16_t* vtb  = (bf16_t*)w; w += SL * 2;                     // 16.78 MB  [BH][T/32][64][32]
  float*  bcat = (float*)w;  w += (size_t)C3 * 4;             // 12 KB
  bf16_t* yb   = xb;  // xb dead after QKV GEMM -> alias

  dim3 tb(32, 8);
  cast_x_kernel<<<8192, 256, 0, stream>>>(x, xb, MM * CC / 4);
  transpose_cast_kernel<<<dim3(32, 32), tb, 0, stream>>>(Wq, btq, 1024, 1024);
  transpose_cast_kernel<<<dim3(64, 32), tb, 0, stream>>>(Wkv, btq + (size_t)1024 * 1024, 1024, 2048);
  transpose_cast_kernel<<<dim3(32, 32), tb, 0, stream>>>(Wp, wpt, 1024, 1024);
  concat_bias_kernel<<<12, 256, 0, stream>>>(bq, bkv, bcat);

  gemm_kernel<1, bf16_t><<<dim3(64 * 24), 256, 0, stream>>>(
      xb, btq, qkvh, bcat, MM, C3, CC, 64, (64 * 24) / 8);
  transpose_v_kernel<<<dim3(TT / 32, HD / 32, BB * HH), tb, 0, stream>>>(qkvh + 2 * SL, vtb);
  attn_kernel<<<dim3(512), 512, 0, stream>>>(qkvh, qkvh + SL, vtb, alibi_m, yb);
  gemm_kernel<0, float><<<dim3(64 * 8), 256, 0, stream>>>(
      yb, wpt, out, bp, MM, CC, CC, 64, (64 * 8) / 8);
}